// Round 5
// baseline (228.265 us; speedup 1.0000x reference)
//
#include <hip/hip_runtime.h>
#include <hip/hip_bf16.h>

// Problem constants
#define B_ROWS 4096
#define N_ROWS 8192
#define D_DIM 256
#define PHI 0.95f
// exp(sim-2) = exp2((2*raw-2)*log2e) = exp2(raw*C1 - C1)
#define C1 2.8853900817779268f

// Symmetric tiling: upper-triangle over 256-row x 256-col blocks.
// Block (bi,bj), bj>=bi. 4 waves own 64-row stripes Rw=4bi+wave; 4 staged
// col-tiles of 64 (C=4bj+ct).
#define RB 32                                   // 256-row stripes
#define NBLK (RB * (RB + 1) / 2)                // 528 blocks
#define LDS_STRIDE 264                          // shorts; baseline-proven pad
#define NSLICE 33                               // 32 pair-slices + 1 diag-col

typedef __attribute__((ext_vector_type(8))) short short8;    // 8 x bf16
typedef __attribute__((ext_vector_type(4))) float floatx4;   // MFMA C/D

static __device__ __forceinline__ unsigned short f2bf(float f) {
    unsigned u = __builtin_bit_cast(unsigned, f);
    unsigned r = (u + 0x7fffu + ((u >> 16) & 1u)) >> 16;   // RNE
    return (unsigned short)r;
}
static __device__ __forceinline__ float bf2f(unsigned short s) {
    unsigned u = ((unsigned)s) << 16;
    return __builtin_bit_cast(float, u);
}
static __device__ __forceinline__ float fast_exp2(float x) {
#if __has_builtin(__builtin_amdgcn_exp2f)
    return __builtin_amdgcn_exp2f(x);
#else
    return __expf(x * 0.6931471805599453f);
#endif
}

// Kernel 1: fused normalize + positive-pair dot (verified rounds 2-4).
// acc[0..8191] zeroed for the fallback-atomic path (harmless in slice mode:
// slice 0 is fully overwritten by plain stores).
__global__ __launch_bounds__(256) void norm_pos_kernel(
        const float* __restrict__ feat, unsigned short* __restrict__ X,
        float* __restrict__ acc, float* __restrict__ rawp,
        float* __restrict__ out) {
    int pair = blockIdx.x * 4 + (threadIdx.x >> 6);   // 0..4095
    int lane = threadIdx.x & 63;
    const float* src = feat + (size_t)pair * (2 * D_DIM);
    float4 v0 = ((const float4*)src)[lane];           // view 0
    float4 v1 = ((const float4*)(src + D_DIM))[lane]; // view 1
    float ss0 = v0.x * v0.x + v0.y * v0.y + v0.z * v0.z + v0.w * v0.w;
    float ss1 = v1.x * v1.x + v1.y * v1.y + v1.z * v1.z + v1.w * v1.w;
    #pragma unroll
    for (int off = 32; off; off >>= 1) {
        ss0 += __shfl_xor(ss0, off);
        ss1 += __shfl_xor(ss1, off);
    }
    float inv0 = 1.0f / fmaxf(sqrtf(ss0), 1e-12f);
    float inv1 = 1.0f / fmaxf(sqrtf(ss1), 1e-12f);
    ushort4 o0, o1;
    o0.x = f2bf(v0.x * inv0); o0.y = f2bf(v0.y * inv0);
    o0.z = f2bf(v0.z * inv0); o0.w = f2bf(v0.w * inv0);
    o1.x = f2bf(v1.x * inv1); o1.y = f2bf(v1.y * inv1);
    o1.z = f2bf(v1.z * inv1); o1.w = f2bf(v1.w * inv1);
    ((ushort4*)(X + (size_t)pair * D_DIM))[lane] = o0;
    ((ushort4*)(X + (size_t)(pair + B_ROWS) * D_DIM))[lane] = o1;
    float d = bf2f(o0.x) * bf2f(o1.x) + bf2f(o0.y) * bf2f(o1.y)
            + bf2f(o0.z) * bf2f(o1.z) + bf2f(o0.w) * bf2f(o1.w);
    #pragma unroll
    for (int off = 32; off; off >>= 1) d += __shfl_xor(d, off);
    if (lane == 0) {
        rawp[pair] = d; rawp[pair + B_ROWS] = d;   // symmetric
        acc[pair] = 0.0f; acc[pair + B_ROWS] = 0.0f;
    }
    if (blockIdx.x == 0 && threadIdx.x == 0) out[0] = 0.0f;
}

// Kernel 2: symmetric Gram + masked exp-sum. Round-4-verified compute
// (33KB padded LDS stage, A-frags once/block, 2 barriers/tile, triangle
// decode, row + transpose reductions) — but ZERO global atomics in slice
// mode: disjoint-by-construction plain stores into 33 partial slices.
//   block (bi,bj): row partials  -> slice bj, segment bi*256  (per-wave rows)
//                  col partials  -> slice (bi==bj ? 32 : bi), segment bj*256
// Every slice element is written exactly once -> no zeroing, no races.
__global__ __launch_bounds__(256, 4) void sym_sim_kernel(
        const unsigned short* __restrict__ X, float* __restrict__ acc,
        int use_slices) {
    __shared__ unsigned short tile[64 * LDS_STRIDE];   // 33,792 B
    __shared__ float col_lds[4][256];                  //  4,096 B

    const int tid  = threadIdx.x;
    const int wave = tid >> 6;
    const int lane = tid & 63;
    const int quad = lane >> 4;
    const int l16  = lane & 15;

    // zero col_lds (completes before the first __syncthreads below)
    col_lds[0][tid & 255] = 0.0f; col_lds[1][tid & 255] = 0.0f;
    col_lds[2][tid & 255] = 0.0f; col_lds[3][tid & 255] = 0.0f;

    // bid -> (bi, bj), pairs ordered by bi with bj = bi..RB-1 (verified r4)
    const int bid = (int)blockIdx.x;
    int bi = 0, off = 0;
    while (off + (RB - bi) <= bid) { off += RB - bi; bi++; }
    const int bj = bi + (bid - off);

    const int rowbase = bi * 256 + wave * 64;   // this wave's 64 rows
    const int Rw = bi * 4 + wave;               // wave's 64-row stripe index

    // A fragments: 4 row-sets x 8 K-steps; lane holds A[m=l16][k=quad*8+j]
    short8 af[4][8];
    #pragma unroll
    for (int s = 0; s < 4; s++) {
        const unsigned short* ap = X + (size_t)(rowbase + s * 16 + l16) * D_DIM + quad * 8;
        #pragma unroll
        for (int ks = 0; ks < 8; ks++)
            af[s][ks] = *(const short8*)(ap + ks * 32);
    }

    float sacc[4][4];                            // row sums, carried over cts
    #pragma unroll
    for (int s = 0; s < 4; s++)
        #pragma unroll
        for (int r = 0; r < 4; r++) sacc[s][r] = 0.0f;

    for (int ct = 0; ct < 4; ct++) {
        const int C = bj * 4 + ct;               // global 64-col tile index
        const int cbase = C * 64;
        __syncthreads();
        #pragma unroll
        for (int p = 0; p < 8; p++) {            // stage 64 rows x 256 cols
            int idx = p * 256 + tid;
            int r   = idx >> 5;
            int ch  = idx & 31;
            short8 d = *(const short8*)(X + (size_t)(cbase + r) * D_DIM + ch * 8);
            *(short8*)(tile + r * LDS_STRIDE + ch * 8) = d;
        }
        __syncthreads();

        if (C < Rw) continue;                    // below diagonal: skip

        float cacc[4];
        #pragma unroll
        for (int st = 0; st < 4; st++) {         // 4 col-subtiles of 16
            const unsigned short* bp = tile + (st * 16 + l16) * LDS_STRIDE + quad * 8;
            floatx4 a4[4];
            #pragma unroll
            for (int s = 0; s < 4; s++) a4[s] = (floatx4){0.f, 0.f, 0.f, 0.f};
            #pragma unroll
            for (int ks = 0; ks < 8; ks++) {     // K = 256
                short8 bfrag = *(const short8*)(bp + ks * 32);
                #pragma unroll
                for (int s = 0; s < 4; s++)
                    a4[s] = __builtin_amdgcn_mfma_f32_16x16x32_bf16(af[s][ks], bfrag, a4[s], 0, 0, 0);
            }
            // Epilogue: element (s,st,r) = (row rowbase+s*16+quad*4+r,
            //                               col cbase+st*16+l16)
            float cs = 0.0f;
            #pragma unroll
            for (int s = 0; s < 4; s++)
                #pragma unroll
                for (int r = 0; r < 4; r++) {
                    float raw = a4[s][r];
                    float e = fast_exp2(fmaf(raw, C1, -C1));
                    e = (raw < PHI) ? e : 0.0f;
                    sacc[s][r] += e;
                    cs += e;
                }
            cacc[st] = cs;
        }
        // Transpose (col) partials for above-diagonal tiles only.
        if (C > Rw) {
            #pragma unroll
            for (int st = 0; st < 4; st++) {
                float v = cacc[st];
                v += __shfl_xor(v, 16);
                v += __shfl_xor(v, 32);
                if (use_slices) {
                    if (quad == 0) col_lds[wave][ct * 64 + st * 16 + l16] = v;
                } else {
                    if (quad == 0) atomicAdd(&acc[cbase + st * 16 + l16], v);
                }
            }
        }
    }

    // Row sums: reduce over the 16 cols (l16) of each quad-group (verified).
    #pragma unroll
    for (int s = 0; s < 4; s++)
        #pragma unroll
        for (int r = 0; r < 4; r++) {
            float v = sacc[s][r];
            v += __shfl_xor(v, 1);
            v += __shfl_xor(v, 2);
            v += __shfl_xor(v, 4);
            v += __shfl_xor(v, 8);
            if (use_slices) {
                if (l16 == r)
                    acc[(size_t)bj * N_ROWS + rowbase + s * 16 + quad * 4 + r] = v;
            } else {
                if (l16 == r)
                    atomicAdd(&acc[rowbase + s * 16 + quad * 4 + r], v);
            }
        }

    // Col partials: combine the 4 waves' LDS copies, one plain store each.
    if (use_slices) {
        __syncthreads();
        int c = tid;                       // block-local col 0..255
        float v = col_lds[0][c] + col_lds[1][c] + col_lds[2][c] + col_lds[3][c];
        int slice = (bi == bj) ? 32 : bi;
        acc[(size_t)slice * N_ROWS + bj * 256 + c] = v;
    }
}

// Kernel 3: loss = mean(2 + log(S_i + pos-correction) - P_i).
// Slice mode: S_i = sum of 33 disjoint partial slices.
__global__ __launch_bounds__(256) void finalize_kernel(
        const float* __restrict__ acc, const float* __restrict__ rawp,
        float* __restrict__ out, int use_slices) {
    __shared__ float red[4];
    int i = blockIdx.x * 256 + threadIdx.x;
    float Sv;
    if (use_slices) {
        Sv = 0.0f;
        #pragma unroll
        for (int s = 0; s < NSLICE; s++) Sv += acc[(size_t)s * N_ROWS + i];
    } else {
        Sv = acc[i];
    }
    float rp = rawp[i];
    float pclip = fminf(fmaxf(rp, -1.0f), 1.0f);
    float psim = 2.0f * pclip;
    Sv += (rp >= PHI) ? __expf(psim - 2.0f) : 0.0f;
    float v = 2.0f + logf(Sv) - psim;
    #pragma unroll
    for (int off = 32; off; off >>= 1) v += __shfl_xor(v, off);
    int lane = threadIdx.x & 63, wave = threadIdx.x >> 6;
    if (lane == 0) red[wave] = v;
    __syncthreads();
    if (threadIdx.x == 0) {
        float t = red[0] + red[1] + red[2] + red[3];
        atomicAdd(out, t * (1.0f / (float)N_ROWS));
    }
}

extern "C" void kernel_launch(void* const* d_in, const int* in_sizes, int n_in,
                              void* d_out, int out_size, void* d_ws, size_t ws_size,
                              hipStream_t stream) {
    const float* feat = (const float*)d_in[0];
    float* out = (float*)d_out;

    unsigned short* X = (unsigned short*)d_ws;
    float* rawp = (float*)((char*)d_ws + (size_t)N_ROWS * D_DIM * 2);
    float* acc  = rawp + N_ROWS;   // slice mode: 33*8192 f32; fallback: 8192

    size_t need = (size_t)N_ROWS * D_DIM * 2      // X
                + (size_t)N_ROWS * 4              // rawp
                + (size_t)NSLICE * N_ROWS * 4;    // partial slices
    int use_slices = (ws_size >= need) ? 1 : 0;

    norm_pos_kernel<<<B_ROWS / 4, 256, 0, stream>>>(feat, X, acc, rawp, out);
    sym_sim_kernel<<<NBLK, 256, 0, stream>>>(X, acc, use_slices);
    finalize_kernel<<<N_ROWS / 256, 256, 0, stream>>>(acc, rawp, out, use_slices);
}

// Round 7
// 168.187 us; speedup vs baseline: 1.3572x; 1.3572x over previous
//
#include <hip/hip_runtime.h>
#include <hip/hip_bf16.h>

// Problem constants
#define B_ROWS 4096
#define N_ROWS 8192
#define D_DIM 256
#define PHI 0.95f
// exp(sim-2) = exp2((2*raw-2)*log2e) = exp2(raw*C1 - C1)
#define C1 2.8853900817779268f

// Symmetric tiling: upper-triangle over 256-row x 256-col blocks.
// Block (bi,bj), bj>=bi. 4 waves own 64-row stripes Rw=4bi+wave; 4 staged
// col-tiles of 64 (C=4bj+ct).
#define RB 32                                   // 256-row stripes
#define NBLK (RB * (RB + 1) / 2)                // 528 blocks
#define LDS_STRIDE 264                          // shorts; baseline-proven pad
#define NSLICE 33                               // 32 pair-slices + 1 diag-col

typedef __attribute__((ext_vector_type(8))) short short8;    // 8 x bf16
typedef __attribute__((ext_vector_type(4))) float floatx4;   // MFMA C/D

static __device__ __forceinline__ unsigned short f2bf(float f) {
    unsigned u = __builtin_bit_cast(unsigned, f);
    unsigned r = (u + 0x7fffu + ((u >> 16) & 1u)) >> 16;   // RNE
    return (unsigned short)r;
}
static __device__ __forceinline__ float bf2f(unsigned short s) {
    unsigned u = ((unsigned)s) << 16;
    return __builtin_bit_cast(float, u);
}
static __device__ __forceinline__ float fast_exp2(float x) {
#if __has_builtin(__builtin_amdgcn_exp2f)
    return __builtin_amdgcn_exp2f(x);
#else
    return __expf(x * 0.6931471805599453f);
#endif
}

// Kernel 1: fused normalize + positive-pair dot (verified rounds 2-5).
// acc[0..8191] zeroed for the fallback-atomic path (harmless in slice mode:
// slice 0 is fully overwritten by plain stores).
__global__ __launch_bounds__(256) void norm_pos_kernel(
        const float* __restrict__ feat, unsigned short* __restrict__ X,
        float* __restrict__ acc, float* __restrict__ rawp,
        float* __restrict__ out) {
    int pair = blockIdx.x * 4 + (threadIdx.x >> 6);   // 0..4095
    int lane = threadIdx.x & 63;
    const float* src = feat + (size_t)pair * (2 * D_DIM);
    float4 v0 = ((const float4*)src)[lane];           // view 0
    float4 v1 = ((const float4*)(src + D_DIM))[lane]; // view 1
    float ss0 = v0.x * v0.x + v0.y * v0.y + v0.z * v0.z + v0.w * v0.w;
    float ss1 = v1.x * v1.x + v1.y * v1.y + v1.z * v1.z + v1.w * v1.w;
    #pragma unroll
    for (int off = 32; off; off >>= 1) {
        ss0 += __shfl_xor(ss0, off);
        ss1 += __shfl_xor(ss1, off);
    }
    float inv0 = 1.0f / fmaxf(sqrtf(ss0), 1e-12f);
    float inv1 = 1.0f / fmaxf(sqrtf(ss1), 1e-12f);
    ushort4 o0, o1;
    o0.x = f2bf(v0.x * inv0); o0.y = f2bf(v0.y * inv0);
    o0.z = f2bf(v0.z * inv0); o0.w = f2bf(v0.w * inv0);
    o1.x = f2bf(v1.x * inv1); o1.y = f2bf(v1.y * inv1);
    o1.z = f2bf(v1.z * inv1); o1.w = f2bf(v1.w * inv1);
    ((ushort4*)(X + (size_t)pair * D_DIM))[lane] = o0;
    ((ushort4*)(X + (size_t)(pair + B_ROWS) * D_DIM))[lane] = o1;
    float d = bf2f(o0.x) * bf2f(o1.x) + bf2f(o0.y) * bf2f(o1.y)
            + bf2f(o0.z) * bf2f(o1.z) + bf2f(o0.w) * bf2f(o1.w);
    #pragma unroll
    for (int off = 32; off; off >>= 1) d += __shfl_xor(d, off);
    if (lane == 0) {
        rawp[pair] = d; rawp[pair + B_ROWS] = d;   // symmetric
        acc[pair] = 0.0f; acc[pair + B_ROWS] = 0.0f;
    }
    if (blockIdx.x == 0 && threadIdx.x == 0) out[0] = 0.0f;
}

// Kernel 2: symmetric Gram + masked exp-sum. Round-4-verified compute
// (33KB padded LDS stage, A-frags once/block, 2 barriers/tile, triangle
// decode, row + transpose reductions); ZERO global atomics in slice mode:
// disjoint-by-construction plain stores into 33 partial slices.
//   block (bi,bj): row partials  -> slice bj, segment bi*256  (per-wave rows)
//                  col partials  -> slice (bi==bj ? 32 : bi), segment bj*256
// Every slice element is written exactly once -> no zeroing, no races.
// launch_bounds (256,2): r5's (256,4) forced a 64-VGPR cap -> af[] spilled
// to scratch (218 MB scratch writes). 128 VGPR needs 2 waves/EU max.
__global__ __launch_bounds__(256, 2) void sym_sim_kernel(
        const unsigned short* __restrict__ X, float* __restrict__ acc,
        int use_slices) {
    __shared__ unsigned short tile[64 * LDS_STRIDE];   // 33,792 B
    __shared__ float col_lds[4][256];                  //  4,096 B

    const int tid  = threadIdx.x;
    const int wave = tid >> 6;
    const int lane = tid & 63;
    const int quad = lane >> 4;
    const int l16  = lane & 15;

    // zero col_lds (completes before the first __syncthreads below)
    col_lds[0][tid & 255] = 0.0f; col_lds[1][tid & 255] = 0.0f;
    col_lds[2][tid & 255] = 0.0f; col_lds[3][tid & 255] = 0.0f;

    // bid -> (bi, bj), pairs ordered by bi with bj = bi..RB-1 (verified r4)
    const int bid = (int)blockIdx.x;
    int bi = 0, off = 0;
    while (off + (RB - bi) <= bid) { off += RB - bi; bi++; }
    const int bj = bi + (bid - off);

    const int rowbase = bi * 256 + wave * 64;   // this wave's 64 rows
    const int Rw = bi * 4 + wave;               // wave's 64-row stripe index

    // A fragments: 4 row-sets x 8 K-steps; lane holds A[m=l16][k=quad*8+j]
    short8 af[4][8];
    #pragma unroll
    for (int s = 0; s < 4; s++) {
        const unsigned short* ap = X + (size_t)(rowbase + s * 16 + l16) * D_DIM + quad * 8;
        #pragma unroll
        for (int ks = 0; ks < 8; ks++)
            af[s][ks] = *(const short8*)(ap + ks * 32);
    }

    float sacc[4][4];                            // row sums, carried over cts
    #pragma unroll
    for (int s = 0; s < 4; s++)
        #pragma unroll
        for (int r = 0; r < 4; r++) sacc[s][r] = 0.0f;

    for (int ct = 0; ct < 4; ct++) {
        const int C = bj * 4 + ct;               // global 64-col tile index
        const int cbase = C * 64;
        __syncthreads();
        #pragma unroll
        for (int p = 0; p < 8; p++) {            // stage 64 rows x 256 cols
            int idx = p * 256 + tid;
            int r   = idx >> 5;
            int ch  = idx & 31;
            short8 d = *(const short8*)(X + (size_t)(cbase + r) * D_DIM + ch * 8);
            *(short8*)(tile + r * LDS_STRIDE + ch * 8) = d;
        }
        __syncthreads();

        if (C < Rw) continue;                    // below diagonal: skip

        float cacc[4];
        #pragma unroll
        for (int st = 0; st < 4; st++) {         // 4 col-subtiles of 16
            const unsigned short* bp = tile + (st * 16 + l16) * LDS_STRIDE + quad * 8;
            floatx4 a4[4];
            #pragma unroll
            for (int s = 0; s < 4; s++) a4[s] = (floatx4){0.f, 0.f, 0.f, 0.f};
            #pragma unroll
            for (int ks = 0; ks < 8; ks++) {     // K = 256
                short8 bfrag = *(const short8*)(bp + ks * 32);
                #pragma unroll
                for (int s = 0; s < 4; s++)
                    a4[s] = __builtin_amdgcn_mfma_f32_16x16x32_bf16(af[s][ks], bfrag, a4[s], 0, 0, 0);
            }
            // Epilogue: element (s,st,r) = (row rowbase+s*16+quad*4+r,
            //                               col cbase+st*16+l16)
            float cs = 0.0f;
            #pragma unroll
            for (int s = 0; s < 4; s++)
                #pragma unroll
                for (int r = 0; r < 4; r++) {
                    float raw = a4[s][r];
                    float e = fast_exp2(fmaf(raw, C1, -C1));
                    e = (raw < PHI) ? e : 0.0f;
                    sacc[s][r] += e;
                    cs += e;
                }
            cacc[st] = cs;
        }
        // Transpose (col) partials for above-diagonal tiles only.
        if (C > Rw) {
            #pragma unroll
            for (int st = 0; st < 4; st++) {
                float v = cacc[st];
                v += __shfl_xor(v, 16);
                v += __shfl_xor(v, 32);
                if (use_slices) {
                    if (quad == 0) col_lds[wave][ct * 64 + st * 16 + l16] = v;
                } else {
                    if (quad == 0) atomicAdd(&acc[cbase + st * 16 + l16], v);
                }
            }
        }
    }

    // Row sums: reduce over the 16 cols (l16) of each quad-group (verified).
    #pragma unroll
    for (int s = 0; s < 4; s++)
        #pragma unroll
        for (int r = 0; r < 4; r++) {
            float v = sacc[s][r];
            v += __shfl_xor(v, 1);
            v += __shfl_xor(v, 2);
            v += __shfl_xor(v, 4);
            v += __shfl_xor(v, 8);
            if (use_slices) {
                if (l16 == r)
                    acc[(size_t)bj * N_ROWS + rowbase + s * 16 + quad * 4 + r] = v;
            } else {
                if (l16 == r)
                    atomicAdd(&acc[rowbase + s * 16 + quad * 4 + r], v);
            }
        }

    // Col partials: combine the 4 waves' LDS copies, one plain store each.
    if (use_slices) {
        __syncthreads();
        int c = tid;                       // block-local col 0..255
        float v = col_lds[0][c] + col_lds[1][c] + col_lds[2][c] + col_lds[3][c];
        int slice = (bi == bj) ? 32 : bi;
        acc[(size_t)slice * N_ROWS + bj * 256 + c] = v;
    }
}

// Kernel 3: loss = mean(2 + log(S_i + pos-correction) - P_i).
// Slice mode: S_i = sum of 33 disjoint partial slices.
__global__ __launch_bounds__(256) void finalize_kernel(
        const float* __restrict__ acc, const float* __restrict__ rawp,
        float* __restrict__ out, int use_slices) {
    __shared__ float red[4];
    int i = blockIdx.x * 256 + threadIdx.x;
    float Sv;
    if (use_slices) {
        Sv = 0.0f;
        #pragma unroll
        for (int s = 0; s < NSLICE; s++) Sv += acc[(size_t)s * N_ROWS + i];
    } else {
        Sv = acc[i];
    }
    float rp = rawp[i];
    float pclip = fminf(fmaxf(rp, -1.0f), 1.0f);
    float psim = 2.0f * pclip;
    Sv += (rp >= PHI) ? __expf(psim - 2.0f) : 0.0f;
    float v = 2.0f + logf(Sv) - psim;
    #pragma unroll
    for (int off = 32; off; off >>= 1) v += __shfl_xor(v, off);
    int lane = threadIdx.x & 63, wave = threadIdx.x >> 6;
    if (lane == 0) red[wave] = v;
    __syncthreads();
    if (threadIdx.x == 0) {
        float t = red[0] + red[1] + red[2] + red[3];
        atomicAdd(out, t * (1.0f / (float)N_ROWS));
    }
}

extern "C" void kernel_launch(void* const* d_in, const int* in_sizes, int n_in,
                              void* d_out, int out_size, void* d_ws, size_t ws_size,
                              hipStream_t stream) {
    const float* feat = (const float*)d_in[0];
    float* out = (float*)d_out;

    unsigned short* X = (unsigned short*)d_ws;
    float* rawp = (float*)((char*)d_ws + (size_t)N_ROWS * D_DIM * 2);
    float* acc  = rawp + N_ROWS;   // slice mode: 33*8192 f32; fallback: 8192

    size_t need = (size_t)N_ROWS * D_DIM * 2      // X
                + (size_t)N_ROWS * 4              // rawp
                + (size_t)NSLICE * N_ROWS * 4;    // partial slices
    int use_slices = (ws_size >= need) ? 1 : 0;

    norm_pos_kernel<<<B_ROWS / 4, 256, 0, stream>>>(feat, X, acc, rawp, out);
    sym_sim_kernel<<<NBLK, 256, 0, stream>>>(X, acc, use_slices);
    finalize_kernel<<<N_ROWS / 256, 256, 0, stream>>>(acc, rawp, out, use_slices);
}

// Round 8
// 116.466 us; speedup vs baseline: 1.9599x; 1.4441x over previous
//
#include <hip/hip_runtime.h>
#include <hip/hip_bf16.h>

// Problem constants
#define B_ROWS 4096
#define N_ROWS 8192
#define D_DIM 256
#define PHI 0.95f
// exp(sim-2) = exp2((2*raw-2)*log2e) = exp2(raw*C1 - C1)
#define C1 2.8853900817779268f

// Symmetric tiling: upper-triangle over 128x128 blocks. T=64 stripes.
// Block (bi,bj), bj>=bi. 4 waves x 32 rows; 2 staged 64-col tiles.
// Elementwise predicate j>=i handles the diagonal uniformly.
#define TSTRIPE 64
#define NBLK (TSTRIPE * (TSTRIPE + 1) / 2)      // 2080 blocks
#define LDS_STRIDE 264                          // shorts; baseline-proven pad

typedef __attribute__((ext_vector_type(8))) short short8;    // 8 x bf16
typedef __attribute__((ext_vector_type(4))) float floatx4;   // MFMA C/D

static __device__ __forceinline__ unsigned short f2bf(float f) {
    unsigned u = __builtin_bit_cast(unsigned, f);
    unsigned r = (u + 0x7fffu + ((u >> 16) & 1u)) >> 16;   // RNE
    return (unsigned short)r;
}
static __device__ __forceinline__ float bf2f(unsigned short s) {
    unsigned u = ((unsigned)s) << 16;
    return __builtin_bit_cast(float, u);
}
static __device__ __forceinline__ float fast_exp2(float x) {
#if __has_builtin(__builtin_amdgcn_exp2f)
    return __builtin_amdgcn_exp2f(x);
#else
    return __expf(x * 0.6931471805599453f);
#endif
}

// Kernel 1: fused normalize + positive-pair dot (verified rounds 2-7).
__global__ __launch_bounds__(256) void norm_pos_kernel(
        const float* __restrict__ feat, unsigned short* __restrict__ X,
        float* __restrict__ acc, float* __restrict__ rawp,
        float* __restrict__ out) {
    int pair = blockIdx.x * 4 + (threadIdx.x >> 6);   // 0..4095
    int lane = threadIdx.x & 63;
    const float* src = feat + (size_t)pair * (2 * D_DIM);
    float4 v0 = ((const float4*)src)[lane];           // view 0
    float4 v1 = ((const float4*)(src + D_DIM))[lane]; // view 1
    float ss0 = v0.x * v0.x + v0.y * v0.y + v0.z * v0.z + v0.w * v0.w;
    float ss1 = v1.x * v1.x + v1.y * v1.y + v1.z * v1.z + v1.w * v1.w;
    #pragma unroll
    for (int off = 32; off; off >>= 1) {
        ss0 += __shfl_xor(ss0, off);
        ss1 += __shfl_xor(ss1, off);
    }
    float inv0 = 1.0f / fmaxf(sqrtf(ss0), 1e-12f);
    float inv1 = 1.0f / fmaxf(sqrtf(ss1), 1e-12f);
    ushort4 o0, o1;
    o0.x = f2bf(v0.x * inv0); o0.y = f2bf(v0.y * inv0);
    o0.z = f2bf(v0.z * inv0); o0.w = f2bf(v0.w * inv0);
    o1.x = f2bf(v1.x * inv1); o1.y = f2bf(v1.y * inv1);
    o1.z = f2bf(v1.z * inv1); o1.w = f2bf(v1.w * inv1);
    ((ushort4*)(X + (size_t)pair * D_DIM))[lane] = o0;
    ((ushort4*)(X + (size_t)(pair + B_ROWS) * D_DIM))[lane] = o1;
    float d = bf2f(o0.x) * bf2f(o1.x) + bf2f(o0.y) * bf2f(o1.y)
            + bf2f(o0.z) * bf2f(o1.z) + bf2f(o0.w) * bf2f(o1.w);
    #pragma unroll
    for (int off = 32; off; off >>= 1) d += __shfl_xor(d, off);
    if (lane == 0) {
        rawp[pair] = d; rawp[pair + B_ROWS] = d;   // symmetric
        acc[pair] = 0.0f; acc[pair + B_ROWS] = 0.0f;   // atomic-fallback base
    }
    if (blockIdx.x == 0 && threadIdx.x == 0) out[0] = 0.0f;
}

// Kernel 2: symmetric Gram + masked exp-sum. 32-row waves => af[2][8] =
// 64 VGPRs (r4-r7 spilled ~90MB with af[4][8]=128). Uniform elementwise
// predicate j>=i: every element computed contributes row-part (to S[i])
// and, via symmetry, col-part (to S[j]); diagonal is auto-zero (raw>=phi).
// Slice mode (zero atomics): block (bi,bj) plain-stores
//   rowpart[bj][global row]  (128 floats)  at acc[bj*8192 + row]
//   colpart[bi][global col]  (128 floats)  at acc[(64+bi)*8192 + col]
// Every valid segment written exactly once; finalize reads only valid ones.
__global__ __launch_bounds__(256, 2) void sym_sim_kernel(
        const unsigned short* __restrict__ X, float* __restrict__ acc,
        int use_slices) {
    __shared__ unsigned short tile[64 * LDS_STRIDE];   // 33,792 B
    __shared__ float col_lds[4][128];                  //  2,048 B

    const int tid  = threadIdx.x;
    const int wave = tid >> 6;
    const int lane = tid & 63;
    const int quad = lane >> 4;
    const int l16  = lane & 15;

    // bid -> (bi, bj), bj = bi..T-1 (r4-verified pattern, T=64)
    const int bid = (int)blockIdx.x;
    int bi = 0, off = 0;
    while (off + (TSTRIPE - bi) <= bid) { off += TSTRIPE - bi; bi++; }
    const int bj = bi + (bid - off);

    const int rowbase = bi * 128 + wave * 32;   // this wave's 32 rows

    // A fragments: 2 row-sets x 8 K-steps = 64 VGPRs
    short8 af[2][8];
    #pragma unroll
    for (int s = 0; s < 2; s++) {
        const unsigned short* ap = X + (size_t)(rowbase + s * 16 + l16) * D_DIM + quad * 8;
        #pragma unroll
        for (int ks = 0; ks < 8; ks++)
            af[s][ks] = *(const short8*)(ap + ks * 32);
    }

    float sacc[2][4];                            // row sums, carried over cts
    #pragma unroll
    for (int s = 0; s < 2; s++)
        #pragma unroll
        for (int r = 0; r < 4; r++) sacc[s][r] = 0.0f;

    #pragma unroll
    for (int ct = 0; ct < 2; ct++) {
        const int cbase = bj * 128 + ct * 64;    // staged rows of X (cols)
        __syncthreads();
        #pragma unroll
        for (int p = 0; p < 8; p++) {            // stage 64 rows x 256 cols
            int idx = p * 256 + tid;
            int r   = idx >> 5;
            int ch  = idx & 31;
            short8 d = *(const short8*)(X + (size_t)(cbase + r) * D_DIM + ch * 8);
            *(short8*)(tile + r * LDS_STRIDE + ch * 8) = d;
        }
        __syncthreads();

        #pragma unroll
        for (int st = 0; st < 4; st++) {         // 4 col-subtiles of 16
            const unsigned short* bp = tile + (st * 16 + l16) * LDS_STRIDE + quad * 8;
            floatx4 a4[2];
            #pragma unroll
            for (int s = 0; s < 2; s++) a4[s] = (floatx4){0.f, 0.f, 0.f, 0.f};
            #pragma unroll
            for (int ks = 0; ks < 8; ks++) {     // K = 256
                short8 bfrag = *(const short8*)(bp + ks * 32);
                #pragma unroll
                for (int s = 0; s < 2; s++)
                    a4[s] = __builtin_amdgcn_mfma_f32_16x16x32_bf16(af[s][ks], bfrag, a4[s], 0, 0, 0);
            }
            // Epilogue: element (s,r) x lane = (i = rowbase+s*16+quad*4+r,
            //                                   j = cbase+st*16+l16)
            const int jv = cbase + st * 16 + l16;
            float cs = 0.0f;
            #pragma unroll
            for (int s = 0; s < 2; s++) {
                const int ib = rowbase + s * 16 + quad * 4;
                #pragma unroll
                for (int r = 0; r < 4; r++) {
                    float raw = a4[s][r];
                    float e = fast_exp2(fmaf(raw, C1, -C1));
                    e = (raw < PHI) ? e : 0.0f;
                    e = (jv >= ib + r) ? e : 0.0f;   // upper-tri predicate
                    sacc[s][r] += e;
                    cs += e;
                }
            }
            // col partial for col jv: reduce over quads (rows of this wave)
            cs += __shfl_xor(cs, 16);
            cs += __shfl_xor(cs, 32);
            if (quad == 0) col_lds[wave][ct * 64 + st * 16 + l16] = cs;
        }
    }

    // Row sums: reduce over the 16 cols (l16) of each quad-group (verified).
    #pragma unroll
    for (int s = 0; s < 2; s++)
        #pragma unroll
        for (int r = 0; r < 4; r++) {
            float v = sacc[s][r];
            v += __shfl_xor(v, 1);
            v += __shfl_xor(v, 2);
            v += __shfl_xor(v, 4);
            v += __shfl_xor(v, 8);
            if (l16 == r) {
                int row = rowbase + s * 16 + quad * 4 + r;
                if (use_slices)
                    acc[(size_t)bj * N_ROWS + row] = v;
                else
                    atomicAdd(&acc[row], v);
            }
        }

    // Col partials: combine 4 waves' LDS rows, one store per block column.
    __syncthreads();
    if (tid < 128) {
        float v = col_lds[0][tid] + col_lds[1][tid]
                + col_lds[2][tid] + col_lds[3][tid];
        int col = bj * 128 + tid;
        if (use_slices)
            acc[(size_t)(TSTRIPE + bi) * N_ROWS + col] = v;
        else
            atomicAdd(&acc[col], v);
    }
}

// Kernel 3: loss = mean(2 + log(S_i + pos-correction) - P_i).
// Slice mode: S_i = sum over valid row-part slices (bj >= si) and
// col-part slices (bi <= si), all reads coalesced across threads.
__global__ __launch_bounds__(256) void finalize_kernel(
        const float* __restrict__ acc, const float* __restrict__ rawp,
        float* __restrict__ out, int use_slices) {
    __shared__ float red[4];
    int i = blockIdx.x * 256 + threadIdx.x;
    float Sv;
    if (use_slices) {
        int si = i >> 7;
        Sv = 0.0f;
        for (int bj = si; bj < TSTRIPE; bj++)
            Sv += acc[(size_t)bj * N_ROWS + i];
        for (int bi = 0; bi <= si; bi++)
            Sv += acc[(size_t)(TSTRIPE + bi) * N_ROWS + i];
    } else {
        Sv = acc[i];
    }
    float rp = rawp[i];
    float pclip = fminf(fmaxf(rp, -1.0f), 1.0f);
    float psim = 2.0f * pclip;
    Sv += (rp >= PHI) ? __expf(psim - 2.0f) : 0.0f;
    float v = 2.0f + logf(Sv) - psim;
    #pragma unroll
    for (int off = 32; off; off >>= 1) v += __shfl_xor(v, off);
    int lane = threadIdx.x & 63, wave = threadIdx.x >> 6;
    if (lane == 0) red[wave] = v;
    __syncthreads();
    if (threadIdx.x == 0) {
        float t = red[0] + red[1] + red[2] + red[3];
        atomicAdd(out, t * (1.0f / (float)N_ROWS));
    }
}

extern "C" void kernel_launch(void* const* d_in, const int* in_sizes, int n_in,
                              void* d_out, int out_size, void* d_ws, size_t ws_size,
                              hipStream_t stream) {
    const float* feat = (const float*)d_in[0];
    float* out = (float*)d_out;

    unsigned short* X = (unsigned short*)d_ws;
    float* rawp = (float*)((char*)d_ws + (size_t)N_ROWS * D_DIM * 2);
    float* acc  = rawp + N_ROWS;   // slice: 128*8192 f32 (4MB); fallback: 8192

    size_t need = (size_t)N_ROWS * D_DIM * 2           // X (4 MB)
                + (size_t)N_ROWS * 4                   // rawp
                + (size_t)2 * TSTRIPE * N_ROWS * 4;    // row+col part slices
    int use_slices = (ws_size >= need) ? 1 : 0;

    norm_pos_kernel<<<B_ROWS / 4, 256, 0, stream>>>(feat, X, acc, rawp, out);
    sym_sim_kernel<<<NBLK, 256, 0, stream>>>(X, acc, use_slices);
    finalize_kernel<<<N_ROWS / 256, 256, 0, stream>>>(acc, rawp, out, use_slices);
}